// Round 6
// baseline (258.922 us; speedup 1.0000x reference)
//
#include <hip/hip_runtime.h>

// Conv_Attention: q,k,v = causal_conv1d(x, W*) ; S = qk^T/sqrt(U);
// softmax over QUERY axis (per-column of S); out = P @ v.
// B=8, T=2048, Cin=U=512, K=3.
//
// Round 13: two levers on the measured ~500 cyc/phase barrier overhead
// (phase wall 894 cyc, MFMA only 387 -> MfmaUtil 46.8%):
//  1. 8 -> 4 phases per 2 K-tiles: each phase runs TWO quadrant MMA calls
//     (24 MFMA/wave QKV, 16 scores/ctx) between one barrier pair. RD order,
//     stage placement, and the counted-vmcnt ledger are unchanged -- only
//     barriers merged. Halves barrier count for all three GEMMs.
//  2. transpose_v + scale_vt2 fused into transpose_scale_v (after scores):
//     1/L[k] is per-thread-constant in the transposed write loop -- kills a
//     full 33.5MB r+w pass and a launch.
//
// vmcnt ledger (GA=4 A-loads/tile, GB=BN/32 B-loads/tile):
//   prologue: B(t0)[GB] A(t0)[GA] B(t1)[GB]; vmcnt(GB) retires t0.
//   pA: reads buf0 {A0,B0,B1}; stages A(t+1)[GA]->buf1.
//   pB: reads buf0 {A1}; stages B(t+2)[GB]->buf0; vmcnt(GB) retires
//       B(t+1)+A(t+1) -> buf1 fully landed before pC reads it.
//   pC/pD symmetric on buf1 (stages A(t+2)->buf0, B(t+3)->buf1).
//   Staging into a buffer region is always preceded by that region's
//   ds_reads + lgkm(0) + barrier (pA reads B-buf0 before pB stages it, etc).

#define B_   8
#define T_   2048
#define D_   512
#define KC_  1536
#define TPAD_ 2050

using short8   = __attribute__((ext_vector_type(8))) short;
using float4v  = __attribute__((ext_vector_type(4))) float;

__device__ __forceinline__ float bf2f(unsigned short b) {
  unsigned u = ((unsigned)b) << 16;
  float f; __builtin_memcpy(&f, &u, 4); return f;
}
__device__ __forceinline__ unsigned short f2bf(float f) {
  unsigned u; __builtin_memcpy(&u, &f, 4);
  u += 0x7fffu + ((u >> 16) & 1u);          // RNE (finite inputs only)
  return (unsigned short)(u >> 16);
}

__device__ __forceinline__ void gld16(const void* g, void* l) {
  __builtin_amdgcn_global_load_lds((__attribute__((address_space(1))) void*)g,
                                   (__attribute__((address_space(3))) void*)l,
                                   16, 0, 0);
}

__device__ __forceinline__ float4v mfma16(short8 a, short8 b, float4v c) {
  return __builtin_amdgcn_mfma_f32_16x16x32_bf16(a, b, c, 0, 0, 0);
}

// ---------------- prep: pad + cast x ----------------
__global__ __launch_bounds__(256) void prep_x(const float* __restrict__ x,
                                              unsigned short* __restrict__ xpad) {
  const int b = blockIdx.y;
  const int i = (blockIdx.x * 256 + threadIdx.x) * 4;   // grid.x=1025 -> exactly 2050*512
  const int t = i >> 9;
  unsigned short* dst = xpad + (size_t)b * (TPAD_ * D_) + i;
  if (t < 2) {
    dst[0] = 0; dst[1] = 0; dst[2] = 0; dst[3] = 0;
  } else {
    const float* sp = x + ((size_t)b * T_ + (t - 2)) * D_ + (i & 511);
    float4v v = *(const float4v*)sp;
    dst[0] = f2bf(v[0]); dst[1] = f2bf(v[1]); dst[2] = f2bf(v[2]); dst[3] = f2bf(v[3]);
  }
}

// ---------------- W transpose (+ bias concat folded in) ----------------
__global__ __launch_bounds__(256) void transpose_w3(const float* __restrict__ Wq,
                                                    const float* __restrict__ Wk,
                                                    const float* __restrict__ Wv,
                                                    unsigned short* __restrict__ Wt,
                                                    const float* __restrict__ bq,
                                                    const float* __restrict__ bk,
                                                    const float* __restrict__ bv,
                                                    float* __restrict__ bcat) {
  __shared__ unsigned short tile[64][65];
  const float* s = (blockIdx.z == 0) ? Wq : (blockIdx.z == 1) ? Wk : Wv;
  unsigned short* d = Wt + (size_t)blockIdx.z * D_ * KC_;
  const int r0 = blockIdx.x * 64, c0 = blockIdx.y * 64;
  const int tc = threadIdx.x & 63, tg = threadIdx.x >> 6;
  if (blockIdx.x == 0 && blockIdx.y == 0) {
    const float* bsrc = (blockIdx.z == 0) ? bq : (blockIdx.z == 1) ? bk : bv;
    bcat[blockIdx.z * 512 + threadIdx.x] = bsrc[threadIdx.x];
    bcat[blockIdx.z * 512 + 256 + threadIdx.x] = bsrc[256 + threadIdx.x];
  }
#pragma unroll
  for (int i = 0; i < 16; i++) {
    const int r = i * 4 + tg;
    tile[r][tc] = f2bf(s[(size_t)(r0 + r) * D_ + (c0 + tc)]);
  }
  __syncthreads();
#pragma unroll
  for (int i = 0; i < 16; i++) {
    const int rr = i * 4 + tg;
    d[(size_t)(c0 + rr) * KC_ + (r0 + tc)] = tile[tc][rr];
  }
}

// ---------------- V transpose + 1/L scale (fused) ----------------
// src: QKV V-slice [k][d] (row stride 1536); dst: Vt[d][k] = V[k][d]/L[k].
// Runs AFTER scores (pl holds full column sums L).
__global__ __launch_bounds__(256) void transpose_scale_v(
    const unsigned short* __restrict__ src, const unsigned short* __restrict__,
    unsigned short* __restrict__ dst, long long sVz,
    const float* __restrict__ pl, long long sPz) {
  __shared__ unsigned short tile[64][65];
  const size_t z = blockIdx.z;
  const unsigned short* s = src + z * (size_t)T_ * KC_;
  unsigned short* d = dst + z * (size_t)sVz;
  const int r0 = blockIdx.x * 64, c0 = blockIdx.y * 64;   // r: k-dim, c: d-dim
  const int tc = threadIdx.x & 63, tg = threadIdx.x >> 6;
#pragma unroll
  for (int i = 0; i < 16; i++) {
    const int r = i * 4 + tg;
    tile[r][tc] = s[(size_t)(r0 + r) * KC_ + (c0 + tc)];
  }
  // k-index of this thread's write column is r0+tc for ALL 16 writes.
  const float myinv = 1.0f / pl[z * (size_t)sPz + (r0 + tc)];
  __syncthreads();
#pragma unroll
  for (int i = 0; i < 16; i++) {
    const int rr = i * 4 + tg;
    d[(size_t)(c0 + rr) * T_ + (r0 + tc)] =
        f2bf(bf2f(tile[tc][rr]) * myinv);
  }
}

// ================= 4-phase BM=128 / 4-wave GEMM: C = A * B'^T =================
// A [M][K] bf16 row-major (lda), B' [N][K] bf16 row-major (ldb), BK=64.
// 256 threads; wave grid 2x2; per-wave output 64 x (BN/2). LDS <= 80KB ->
// 2 blocks/CU so one block's barrier stall hides under the other's MFMA.

#define RD_A(MH, BUF)                                                        \
  {                                                                          \
    const unsigned short* p_ =                                               \
        lds + (BUF) * 8192 + aoff + (MH) * (HFA * 1024);                     \
    _Pragma("unroll") for (int f_ = 0; f_ < HFA; ++f_) {                     \
      afr[MH][f_][0] = *(const short8*)(p_ + f_ * 1024 + q0);                \
      afr[MH][f_][1] = *(const short8*)(p_ + f_ * 1024 + q1);                \
    }                                                                        \
  }

#define RD_B(NH, BUF)                                                        \
  {                                                                          \
    const unsigned short* p_ =                                               \
        lds + 16384 + (BUF) * BLD + boff + (NH) * (HFB * 1024);              \
    _Pragma("unroll") for (int f_ = 0; f_ < HFB; ++f_) {                     \
      bfr[NH][f_][0] = *(const short8*)(p_ + f_ * 1024 + q0);                \
      bfr[NH][f_][1] = *(const short8*)(p_ + f_ * 1024 + q1);                \
    }                                                                        \
  }

#define MMA(MH, NH)                                                          \
  __builtin_amdgcn_s_setprio(1);                                             \
  _Pragma("unroll") for (int s_ = 0; s_ < 2; ++s_)                           \
  _Pragma("unroll") for (int f_ = 0; f_ < HFA; ++f_)                         \
  _Pragma("unroll") for (int g_ = 0; g_ < HFB; ++g_)                         \
      acc[(MH) * HFA + f_][(NH) * HFB + g_] =                                \
          mfma16(afr[MH][f_][s_], bfr[NH][g_][s_],                           \
                 acc[(MH) * HFA + f_][(NH) * HFB + g_]);                     \
  __builtin_amdgcn_s_setprio(0);

#define PH_MID                                                               \
  __builtin_amdgcn_s_barrier();                                              \
  asm volatile("s_waitcnt lgkmcnt(0)" ::: "memory");                         \
  __builtin_amdgcn_sched_barrier(0);

#define PH_END __builtin_amdgcn_s_barrier();

#define VMW                                                                  \
  do {                                                                       \
    if constexpr (GB == 6)                                                   \
      asm volatile("s_waitcnt vmcnt(6)" ::: "memory");                       \
    else                                                                     \
      asm volatile("s_waitcnt vmcnt(4)" ::: "memory");                       \
  } while (0)

template <int MODE, int BN>
__global__ __launch_bounds__(256, 2)
void gemm8(const unsigned short* __restrict__ A, long long sAz, int lda,
           const unsigned short* __restrict__ Bm, long long sBz, int ldb,
           void* __restrict__ Out, long long sOz, int ldo,
           const float* __restrict__ bias,
           float* __restrict__ pl, long long sPz,
           int Kdim, float scale) {
  constexpr int RW  = 64;           // rows per wave (BM=128, wave grid 2x2)
  constexpr int CW  = BN / 2;       // cols per wave
  constexpr int FA  = 4;            // A frags per wave
  constexpr int FB  = CW / 16;      // B frags per wave (6 or 4)
  constexpr int HFA = 2;
  constexpr int HFB = FB / 2;
  constexpr int GB  = BN / 32;      // B staging gld16s per tile (6 or 4)
  constexpr int BLD = BN * 64;      // elems per B buffer
  // A dbuf = 2 x 8192 elems (32KB); B dbuf = 2 x BLD
  __shared__ unsigned short lds[16384 + 2 * BLD];

  const int tid = threadIdx.x;
  const int l = tid & 63;
  const int wv = tid >> 6;
  const int wm = wv >> 1, wn = wv & 1;
  const int l15 = l & 15, hi = l >> 4, l7 = l & 7;
  const size_t z = blockIdx.z;
  const unsigned short* Ab = A + z * (size_t)sAz;
  const unsigned short* Bb = Bm + z * (size_t)sBz;
  const int m0 = blockIdx.x * 128, n0 = blockIdx.y * BN;
  const int NT = Kdim >> 6;
  const int NIT = NT >> 1;

  // ---- staging: LDS linear [row][8 chunks of 16B]; global pre-swizzled
  //      so LDS[row][p] holds global chunk p ^ (row&7). 256 thr -> one gld16
  //      covers 32 rows (4096B).
  const int srow = tid >> 3;                                  // 0..31
  const int cswz = ((tid & 7) ^ ((tid >> 3) & 7)) << 3;       // elem offset
  const unsigned short* gA = Ab + (size_t)(m0 + srow) * lda + cswz;
  const unsigned short* gB = Bb + (size_t)(n0 + srow) * ldb + cswz;

  auto stgA = [&](int buf, int h, int kt) {        // h-th 64-row half
    if (kt >= NT) kt = NT - 1;                      // tail: harmless reload
    unsigned short* d = lds + buf * 8192 + h * 4096 + tid * 8;
    const unsigned short* g = gA + (size_t)(h * 64) * lda + kt * 64;
    gld16(g, d);
    gld16(g + (size_t)32 * lda, d + 2048);
  };
  auto stgB = [&](int buf, int g, int kt) {         // g-th 32-row group
    if (kt >= NT) kt = NT - 1;
    unsigned short* d = lds + 16384 + buf * BLD + g * 2048 + tid * 8;
    const unsigned short* gp = gB + (size_t)(g * 32) * ldb + kt * 64;
    gld16(gp, d);
  };

  // ---- fragment read addressing (inverse swizzle on ds_read_b128)
  const int aoff = (wm * RW + l15) * 64;
  const int boff = (wn * CW + l15) * 64;
  const int q0 = ((0 + hi) ^ l7) << 3;              // k-slice 0 chunk
  const int q1 = ((4 + hi) ^ l7) << 3;              // k-slice 1 chunk

  short8 afr[2][HFA][2];
  short8 bfr[2][HFB][2];
  float4v acc[FA][FB];
#pragma unroll
  for (int i = 0; i < FA; ++i)
#pragma unroll
    for (int j = 0; j < FB; ++j)
#pragma unroll
      for (int r = 0; r < 4; ++r) acc[i][j][r] = 0.f;

  // ---- prologue: tile0 fully + tile1 B; leave tile1.B in flight
#pragma unroll
  for (int g = 0; g < GB; ++g) stgB(0, g, 0);
  stgA(0, 0, 0); stgA(0, 1, 0);
#pragma unroll
  for (int g = 0; g < GB; ++g) stgB(1, g, 1);
  VMW;
  __builtin_amdgcn_s_barrier();
  __builtin_amdgcn_sched_barrier(0);

  // ---- main loop: 4 phases = 2 K-tiles. vmcnt(GB) at pB/pD only.
  for (int it = 0; it < NIT; ++it) {
    const int kt = 2 * it;
    // pA: quadrants (0,0)+(0,1) of buf0 | stage A(t+1)->buf1
    RD_A(0, 0); RD_B(0, 0); RD_B(1, 0);
    stgA(1, 0, kt + 1); stgA(1, 1, kt + 1);
    PH_MID; MMA(0, 0); MMA(0, 1); PH_END;
    // pB: quadrants (1,1)+(1,0) of buf0 | stage B(t+2)->buf0 ; vmcnt
    RD_A(1, 0);
#pragma unroll
    for (int g = 0; g < GB; ++g) stgB(0, g, kt + 2);
    PH_MID; MMA(1, 1); MMA(1, 0); VMW; PH_END;
    // pC: quadrants (0,0)+(0,1) of buf1 | stage A(t+2)->buf0
    RD_A(0, 1); RD_B(0, 1); RD_B(1, 1);
    stgA(0, 0, kt + 2); stgA(0, 1, kt + 2);
    PH_MID; MMA(0, 0); MMA(0, 1); PH_END;
    // pD: quadrants (1,1)+(1,0) of buf1 | stage B(t+3)->buf1 ; vmcnt
    RD_A(1, 1);
#pragma unroll
    for (int g = 0; g < GB; ++g) stgB(1, g, kt + 3);
    PH_MID; MMA(1, 1); MMA(1, 0); VMW; PH_END;
  }

  // ---- epilogue (scalar direct stores -- measured-best form).
  // C/D col = lane&15, row = (lane>>4)*4 + reg.
  const int r0 = m0 + wm * RW + hi * 4;
  const int c0 = n0 + wn * CW + l15;

  if constexpr (MODE == 2) {
    float* O = (float*)Out + z * (size_t)sOz;
#pragma unroll
    for (int fm = 0; fm < FA; ++fm)
#pragma unroll
      for (int fn = 0; fn < FB; ++fn)
#pragma unroll
        for (int r = 0; r < 4; ++r)
          O[(size_t)(r0 + fm * 16 + r) * ldo + (c0 + fn * 16)] =
              acc[fm][fn][r] * scale;
  } else if constexpr (MODE == 0) {
    unsigned short* O = (unsigned short*)Out + z * (size_t)sOz;
#pragma unroll
    for (int fn = 0; fn < FB; ++fn) {
      const float badd = bias[c0 + fn * 16];
#pragma unroll
      for (int fm = 0; fm < FA; ++fm)
#pragma unroll
        for (int r = 0; r < 4; ++r)
          O[(size_t)(r0 + fm * 16 + r) * ldo + (c0 + fn * 16)] =
              f2bf(acc[fm][fn][r] * scale + badd);
    }
  } else {  // MODE 1: P_raw = exp(S*scale - 16) bf16 + atomic column sums
    unsigned short* O = (unsigned short*)Out + z * (size_t)sOz;
    float cs[FB];
#pragma unroll
    for (int fn = 0; fn < FB; ++fn) cs[fn] = 0.f;
#pragma unroll
    for (int fm = 0; fm < FA; ++fm)
#pragma unroll
      for (int fn = 0; fn < FB; ++fn)
#pragma unroll
        for (int r = 0; r < 4; ++r) {
          float e = __expf(acc[fm][fn][r] * scale - 16.f);   // |v| <~ 25
          cs[fn] += e;
          O[(size_t)(r0 + fm * 16 + r) * ldo + (c0 + fn * 16)] = f2bf(e);
        }
    // reduce this wave's 64 rows per column (xor16 folds hi-groups, xor32
    // pairs) then one atomicAdd per column per wm-half (device scope).
#pragma unroll
    for (int fn = 0; fn < FB; ++fn) {
      cs[fn] += __shfl_xor(cs[fn], 16, 64);
      cs[fn] += __shfl_xor(cs[fn], 32, 64);
    }
    if (hi == 0) {
#pragma unroll
      for (int fn = 0; fn < FB; ++fn)
        atomicAdd(&pl[z * (size_t)sPz + (c0 + fn * 16)], cs[fn]);
    }
  }
}

// ---------------- host ----------------
extern "C" void kernel_launch(void* const* d_in, const int* in_sizes, int n_in,
                              void* d_out, int out_size, void* d_ws, size_t ws_size,
                              hipStream_t stream) {
  const float* x  = (const float*)d_in[0];
  const float* Wq = (const float*)d_in[1];
  const float* bq = (const float*)d_in[2];
  const float* Wk = (const float*)d_in[3];
  const float* bk = (const float*)d_in[4];
  const float* Wv = (const float*)d_in[5];
  const float* bv = (const float*)d_in[6];

  char* ws = (char*)d_ws;
  auto alloc = [&](size_t bytes) {
    char* p = ws; ws += (bytes + 255) & ~(size_t)255; return p;
  };
  unsigned short* xpad = (unsigned short*)alloc((size_t)B_ * TPAD_ * D_ * 2);
  unsigned short* Wt   = (unsigned short*)alloc((size_t)KC_ * KC_ * 2);     // [1536 u][1536 k]
  float*          bcat = (float*)alloc((size_t)KC_ * 4);
  unsigned short* QKV  = (unsigned short*)alloc((size_t)B_ * T_ * KC_ * 2); // [B][T][1536]
  unsigned short* Vt   = (unsigned short*)alloc((size_t)B_ * D_ * T_ * 2);
  float* pl   = (float*)alloc((size_t)B_ * T_ * 4);   // colsum L per (z, col)
  size_t used = (size_t)(ws - (char*)d_ws);
  const size_t sAll = (size_t)B_ * T_ * T_ * 2;   // bf16 P, all batches
  const size_t sOne = (size_t)T_ * T_ * 2;
  const int NB = (used + sAll <= ws_size) ? B_ : 1;  // ws-adaptive batching
  unsigned short* Sb = (unsigned short*)alloc(NB == B_ ? sAll : sOne);

  hipMemsetAsync(pl, 0, (size_t)B_ * T_ * 4, stream);
  prep_x<<<dim3(1025, B_), 256, 0, stream>>>(x, xpad);
  transpose_w3<<<dim3(24, 8, 3), 256, 0, stream>>>(Wq, Wk, Wv, Wt,
                                                   bq, bk, bv, bcat);

  // QKV GEMM: M=2048/batch, N=1536, K=1536; BM=128/BN=192 -> 1024 blocks
  // = exactly 2.0 rounds of 512 block-slots (2 blocks/CU, LDS 80KB).
  gemm8<0, 192><<<dim3(16, 8, B_), 256, 0, stream>>>(
      xpad, (long long)TPAD_ * D_, D_,
      Wt, 0, KC_,
      QKV, (long long)T_ * KC_, KC_,
      bcat, nullptr, 0, KC_, 1.0f);

  const float scale = 0.044194173824159216f;  // 1/sqrt(512)
  for (int b0 = 0; b0 < B_; b0 += NB) {
    const unsigned short* Qp = QKV + (size_t)b0 * T_ * KC_;          // +0
    const unsigned short* Kp = QKV + (size_t)b0 * T_ * KC_ + D_;     // +512
    // P_raw = exp(S-16); column sums accumulated atomically into pl[z][col]
    gemm8<1, 128><<<dim3(16, 16, NB), 256, 0, stream>>>(
        Qp, (long long)T_ * KC_, KC_,
        Kp, (long long)T_ * KC_, KC_,
        Sb, (long long)T_ * T_, T_,
        nullptr, pl + (size_t)b0 * T_, (long long)T_,
        D_, scale);
    // Vt[d][k] = V[k][d] / L[k]  (transpose + scale fused, after scores)
    transpose_scale_v<<<dim3(32, 8, NB), 256, 0, stream>>>(
        QKV + (size_t)b0 * T_ * KC_ + 2 * D_, nullptr,
        Vt + (size_t)b0 * D_ * T_, (long long)D_ * T_,
        pl + (size_t)b0 * T_, (long long)T_);
    // ctx: out = P_raw @ Vt'^T, 128x128 tiles -> 512 blocks
    gemm8<2, 128><<<dim3(16, 4, NB), 256, 0, stream>>>(
        Sb, (long long)T_ * T_, T_,
        Vt + (size_t)b0 * D_ * T_, (long long)D_ * T_, T_,
        (float*)d_out + (size_t)b0 * T_ * D_, (long long)T_ * D_, D_,
        nullptr, nullptr, 0, T_, 1.0f);
  }
}

// Round 7
// 249.851 us; speedup vs baseline: 1.0363x; 1.0363x over previous
//
#include <hip/hip_runtime.h>

// Conv_Attention: q,k,v = causal_conv1d(x, W*) ; S = qk^T/sqrt(U);
// softmax over QUERY axis (per-column of S); out = P @ v.
// B=8, T=2048, Cin=U=512, K=3.
//
// Round 14: recombine measured-best halves (3rd time).
//  - K-loop: REVERT to R5/R12 8-phase form. R13's 4-phase merge measured
//    +1.5us on QKV (FETCH 66.7k->76.9k: bursty 6-wide B-staging thrashed L2)
//    and ~+14us total across GEMMs -- barrier count was NOT the cost; with
//    2 blocks/CU barriers already overlap cross-block. 8-phase interleave
//    is load-bearing (m196 agrees).
//  - KEEP R13's transpose_scale_v fusion (saves 33.5MB r/w + launches).
//
// vmcnt ledger (GA=4 A-loads/tile, GB=BN/32 B-loads/tile): prologue
// B(t0)[GB] A(t0)[GA] B(t1)[GB], vmcnt(GB) retires t0; loop p0/p1 +A(t+1),
// p2/p3 +B(t+2), vmcnt(GB) at p3 retires B(t+1)+A(t+1); symmetric p7.
// Never vmcnt(0) in the loop.

#define B_   8
#define T_   2048
#define D_   512
#define KC_  1536
#define TPAD_ 2050

using short8   = __attribute__((ext_vector_type(8))) short;
using float4v  = __attribute__((ext_vector_type(4))) float;

__device__ __forceinline__ float bf2f(unsigned short b) {
  unsigned u = ((unsigned)b) << 16;
  float f; __builtin_memcpy(&f, &u, 4); return f;
}
__device__ __forceinline__ unsigned short f2bf(float f) {
  unsigned u; __builtin_memcpy(&u, &f, 4);
  u += 0x7fffu + ((u >> 16) & 1u);          // RNE (finite inputs only)
  return (unsigned short)(u >> 16);
}

__device__ __forceinline__ void gld16(const void* g, void* l) {
  __builtin_amdgcn_global_load_lds((__attribute__((address_space(1))) void*)g,
                                   (__attribute__((address_space(3))) void*)l,
                                   16, 0, 0);
}

__device__ __forceinline__ float4v mfma16(short8 a, short8 b, float4v c) {
  return __builtin_amdgcn_mfma_f32_16x16x32_bf16(a, b, c, 0, 0, 0);
}

// ---------------- prep: pad + cast x ----------------
__global__ __launch_bounds__(256) void prep_x(const float* __restrict__ x,
                                              unsigned short* __restrict__ xpad) {
  const int b = blockIdx.y;
  const int i = (blockIdx.x * 256 + threadIdx.x) * 4;   // grid.x=1025 -> exactly 2050*512
  const int t = i >> 9;
  unsigned short* dst = xpad + (size_t)b * (TPAD_ * D_) + i;
  if (t < 2) {
    dst[0] = 0; dst[1] = 0; dst[2] = 0; dst[3] = 0;
  } else {
    const float* sp = x + ((size_t)b * T_ + (t - 2)) * D_ + (i & 511);
    float4v v = *(const float4v*)sp;
    dst[0] = f2bf(v[0]); dst[1] = f2bf(v[1]); dst[2] = f2bf(v[2]); dst[3] = f2bf(v[3]);
  }
}

// ---------------- W transpose (+ bias concat folded in) ----------------
__global__ __launch_bounds__(256) void transpose_w3(const float* __restrict__ Wq,
                                                    const float* __restrict__ Wk,
                                                    const float* __restrict__ Wv,
                                                    unsigned short* __restrict__ Wt,
                                                    const float* __restrict__ bq,
                                                    const float* __restrict__ bk,
                                                    const float* __restrict__ bv,
                                                    float* __restrict__ bcat) {
  __shared__ unsigned short tile[64][65];
  const float* s = (blockIdx.z == 0) ? Wq : (blockIdx.z == 1) ? Wk : Wv;
  unsigned short* d = Wt + (size_t)blockIdx.z * D_ * KC_;
  const int r0 = blockIdx.x * 64, c0 = blockIdx.y * 64;
  const int tc = threadIdx.x & 63, tg = threadIdx.x >> 6;
  if (blockIdx.x == 0 && blockIdx.y == 0) {
    const float* bsrc = (blockIdx.z == 0) ? bq : (blockIdx.z == 1) ? bk : bv;
    bcat[blockIdx.z * 512 + threadIdx.x] = bsrc[threadIdx.x];
    bcat[blockIdx.z * 512 + 256 + threadIdx.x] = bsrc[256 + threadIdx.x];
  }
#pragma unroll
  for (int i = 0; i < 16; i++) {
    const int r = i * 4 + tg;
    tile[r][tc] = f2bf(s[(size_t)(r0 + r) * D_ + (c0 + tc)]);
  }
  __syncthreads();
#pragma unroll
  for (int i = 0; i < 16; i++) {
    const int rr = i * 4 + tg;
    d[(size_t)(c0 + rr) * KC_ + (r0 + tc)] = tile[tc][rr];
  }
}

// ---------------- V transpose + 1/L scale (fused) ----------------
// src: QKV V-slice [k][d] (row stride 1536); dst: Vt[d][k] = V[k][d]/L[k].
// Runs AFTER scores (pl holds full column sums L).
__global__ __launch_bounds__(256) void transpose_scale_v(
    const unsigned short* __restrict__ src,
    unsigned short* __restrict__ dst, long long sVz,
    const float* __restrict__ pl, long long sPz) {
  __shared__ unsigned short tile[64][65];
  const size_t z = blockIdx.z;
  const unsigned short* s = src + z * (size_t)T_ * KC_;
  unsigned short* d = dst + z * (size_t)sVz;
  const int r0 = blockIdx.x * 64, c0 = blockIdx.y * 64;   // r: k-dim, c: d-dim
  const int tc = threadIdx.x & 63, tg = threadIdx.x >> 6;
#pragma unroll
  for (int i = 0; i < 16; i++) {
    const int r = i * 4 + tg;
    tile[r][tc] = s[(size_t)(r0 + r) * KC_ + (c0 + tc)];
  }
  // k-index of this thread's write column is r0+tc for ALL 16 writes.
  const float myinv = 1.0f / pl[z * (size_t)sPz + (r0 + tc)];
  __syncthreads();
#pragma unroll
  for (int i = 0; i < 16; i++) {
    const int rr = i * 4 + tg;
    d[(size_t)(c0 + rr) * T_ + (r0 + tc)] =
        f2bf(bf2f(tile[tc][rr]) * myinv);
  }
}

// ================= 8-phase BM=128 / 4-wave GEMM: C = A * B'^T =================
// A [M][K] bf16 row-major (lda), B' [N][K] bf16 row-major (ldb), BK=64.
// 256 threads; wave grid 2x2; per-wave output 64 x (BN/2). LDS <= 80KB ->
// 2 blocks/CU so one block's barrier stall hides under the other's MFMA.

#define RD_A(MH, BUF)                                                        \
  {                                                                          \
    const unsigned short* p_ =                                               \
        lds + (BUF) * 8192 + aoff + (MH) * (HFA * 1024);                     \
    _Pragma("unroll") for (int f_ = 0; f_ < HFA; ++f_) {                     \
      afr[MH][f_][0] = *(const short8*)(p_ + f_ * 1024 + q0);                \
      afr[MH][f_][1] = *(const short8*)(p_ + f_ * 1024 + q1);                \
    }                                                                        \
  }

#define RD_B(NH, BUF)                                                        \
  {                                                                          \
    const unsigned short* p_ =                                               \
        lds + 16384 + (BUF) * BLD + boff + (NH) * (HFB * 1024);              \
    _Pragma("unroll") for (int f_ = 0; f_ < HFB; ++f_) {                     \
      bfr[NH][f_][0] = *(const short8*)(p_ + f_ * 1024 + q0);                \
      bfr[NH][f_][1] = *(const short8*)(p_ + f_ * 1024 + q1);                \
    }                                                                        \
  }

#define MMA(MH, NH)                                                          \
  __builtin_amdgcn_s_setprio(1);                                             \
  _Pragma("unroll") for (int s_ = 0; s_ < 2; ++s_)                           \
  _Pragma("unroll") for (int f_ = 0; f_ < HFA; ++f_)                         \
  _Pragma("unroll") for (int g_ = 0; g_ < HFB; ++g_)                         \
      acc[(MH) * HFA + f_][(NH) * HFB + g_] =                                \
          mfma16(afr[MH][f_][s_], bfr[NH][g_][s_],                           \
                 acc[(MH) * HFA + f_][(NH) * HFB + g_]);                     \
  __builtin_amdgcn_s_setprio(0);

#define PH_MID                                                               \
  __builtin_amdgcn_s_barrier();                                              \
  asm volatile("s_waitcnt lgkmcnt(0)" ::: "memory");                         \
  __builtin_amdgcn_sched_barrier(0);

#define PH_END __builtin_amdgcn_s_barrier();

#define VMW                                                                  \
  do {                                                                       \
    if constexpr (GB == 6)                                                   \
      asm volatile("s_waitcnt vmcnt(6)" ::: "memory");                       \
    else                                                                     \
      asm volatile("s_waitcnt vmcnt(4)" ::: "memory");                       \
  } while (0)

template <int MODE, int BN>
__global__ __launch_bounds__(256, 2)
void gemm8(const unsigned short* __restrict__ A, long long sAz, int lda,
           const unsigned short* __restrict__ Bm, long long sBz, int ldb,
           void* __restrict__ Out, long long sOz, int ldo,
           const float* __restrict__ bias,
           float* __restrict__ pl, long long sPz,
           int Kdim, float scale) {
  constexpr int RW  = 64;           // rows per wave (BM=128, wave grid 2x2)
  constexpr int CW  = BN / 2;       // cols per wave
  constexpr int FA  = 4;            // A frags per wave
  constexpr int FB  = CW / 16;      // B frags per wave (6 or 4)
  constexpr int HFA = 2;
  constexpr int HFB = FB / 2;
  constexpr int GB  = BN / 32;      // B staging gld16s per tile (6 or 4)
  constexpr int GBP2 = GB / 2;
  constexpr int BLD = BN * 64;      // elems per B buffer
  // A dbuf = 2 x 8192 elems (32KB); B dbuf = 2 x BLD
  __shared__ unsigned short lds[16384 + 2 * BLD];

  const int tid = threadIdx.x;
  const int l = tid & 63;
  const int wv = tid >> 6;
  const int wm = wv >> 1, wn = wv & 1;
  const int l15 = l & 15, hi = l >> 4, l7 = l & 7;
  const size_t z = blockIdx.z;
  const unsigned short* Ab = A + z * (size_t)sAz;
  const unsigned short* Bb = Bm + z * (size_t)sBz;
  const int m0 = blockIdx.x * 128, n0 = blockIdx.y * BN;
  const int NT = Kdim >> 6;
  const int NIT = NT >> 1;

  // ---- staging: LDS linear [row][8 chunks of 16B]; global pre-swizzled
  //      so LDS[row][p] holds global chunk p ^ (row&7). 256 thr -> one gld16
  //      covers 32 rows (4096B).
  const int srow = tid >> 3;                                  // 0..31
  const int cswz = ((tid & 7) ^ ((tid >> 3) & 7)) << 3;       // elem offset
  const unsigned short* gA = Ab + (size_t)(m0 + srow) * lda + cswz;
  const unsigned short* gB = Bb + (size_t)(n0 + srow) * ldb + cswz;

  auto stgA = [&](int buf, int h, int kt) {        // h-th 64-row half
    if (kt >= NT) kt = NT - 1;                      // tail: harmless reload
    unsigned short* d = lds + buf * 8192 + h * 4096 + tid * 8;
    const unsigned short* g = gA + (size_t)(h * 64) * lda + kt * 64;
    gld16(g, d);
    gld16(g + (size_t)32 * lda, d + 2048);
  };
  auto stgB = [&](int buf, int g, int kt) {         // g-th 32-row group
    if (kt >= NT) kt = NT - 1;
    unsigned short* d = lds + 16384 + buf * BLD + g * 2048 + tid * 8;
    const unsigned short* gp = gB + (size_t)(g * 32) * ldb + kt * 64;
    gld16(gp, d);
  };

  // ---- fragment read addressing (inverse swizzle on ds_read_b128)
  const int aoff = (wm * RW + l15) * 64;
  const int boff = (wn * CW + l15) * 64;
  const int q0 = ((0 + hi) ^ l7) << 3;              // k-slice 0 chunk
  const int q1 = ((4 + hi) ^ l7) << 3;              // k-slice 1 chunk

  short8 afr[2][HFA][2];
  short8 bfr[2][HFB][2];
  float4v acc[FA][FB];
#pragma unroll
  for (int i = 0; i < FA; ++i)
#pragma unroll
    for (int j = 0; j < FB; ++j)
#pragma unroll
      for (int r = 0; r < 4; ++r) acc[i][j][r] = 0.f;

  // ---- prologue: tile0 fully + tile1 B; leave tile1.B in flight
#pragma unroll
  for (int g = 0; g < GB; ++g) stgB(0, g, 0);
  stgA(0, 0, 0); stgA(0, 1, 0);
#pragma unroll
  for (int g = 0; g < GB; ++g) stgB(1, g, 1);
  VMW;
  __builtin_amdgcn_s_barrier();
  __builtin_amdgcn_sched_barrier(0);

  // ---- main loop: 8 phases = 2 K-tiles. vmcnt(GB) at p3/p7 only.
  for (int it = 0; it < NIT; ++it) {
    const int kt = 2 * it;
    // p0: q(0,0) buf0      | stage A0(t+1)->buf1
    RD_A(0, 0); RD_B(0, 0);
    stgA(1, 0, kt + 1);
    PH_MID; MMA(0, 0); PH_END;
    // p1: q(0,1) buf0      | stage A1(t+1)->buf1
    RD_B(1, 0);
    stgA(1, 1, kt + 1);
    PH_MID; MMA(0, 1); PH_END;
    // p2: q(1,1) buf0      | stage B[0..GBP2)(t+2)->buf0
    RD_A(1, 0);
#pragma unroll
    for (int g = 0; g < GBP2; ++g) stgB(0, g, kt + 2);
    PH_MID; MMA(1, 1); PH_END;
    // p3: q(1,0) buf0      | stage B[GBP2..GB)(t+2)->buf0 ; vmcnt -> t+1 landed
#pragma unroll
    for (int g = GBP2; g < GB; ++g) stgB(0, g, kt + 2);
    PH_MID; MMA(1, 0); VMW; PH_END;
    // p4: q(0,0) buf1      | stage A0(t+2)->buf0
    RD_A(0, 1); RD_B(0, 1);
    stgA(0, 0, kt + 2);
    PH_MID; MMA(0, 0); PH_END;
    // p5: q(0,1) buf1      | stage A1(t+2)->buf0
    RD_B(1, 1);
    stgA(0, 1, kt + 2);
    PH_MID; MMA(0, 1); PH_END;
    // p6: q(1,1) buf1      | stage B[0..GBP2)(t+3)->buf1
    RD_A(1, 1);
#pragma unroll
    for (int g = 0; g < GBP2; ++g) stgB(1, g, kt + 3);
    PH_MID; MMA(1, 1); PH_END;
    // p7: q(1,0) buf1      | stage B[GBP2..GB)(t+3)->buf1 ; vmcnt -> t+2 landed
#pragma unroll
    for (int g = GBP2; g < GB; ++g) stgB(1, g, kt + 3);
    PH_MID; MMA(1, 0); VMW; PH_END;
  }

  // ---- epilogue (scalar direct stores -- measured-best form).
  // C/D col = lane&15, row = (lane>>4)*4 + reg.
  const int r0 = m0 + wm * RW + hi * 4;
  const int c0 = n0 + wn * CW + l15;

  if constexpr (MODE == 2) {
    float* O = (float*)Out + z * (size_t)sOz;
#pragma unroll
    for (int fm = 0; fm < FA; ++fm)
#pragma unroll
      for (int fn = 0; fn < FB; ++fn)
#pragma unroll
        for (int r = 0; r < 4; ++r)
          O[(size_t)(r0 + fm * 16 + r) * ldo + (c0 + fn * 16)] =
              acc[fm][fn][r] * scale;
  } else if constexpr (MODE == 0) {
    unsigned short* O = (unsigned short*)Out + z * (size_t)sOz;
#pragma unroll
    for (int fn = 0; fn < FB; ++fn) {
      const float badd = bias[c0 + fn * 16];
#pragma unroll
      for (int fm = 0; fm < FA; ++fm)
#pragma unroll
        for (int r = 0; r < 4; ++r)
          O[(size_t)(r0 + fm * 16 + r) * ldo + (c0 + fn * 16)] =
              f2bf(acc[fm][fn][r] * scale + badd);
    }
  } else {  // MODE 1: P_raw = exp(S*scale - 16) bf16 + atomic column sums
    unsigned short* O = (unsigned short*)Out + z * (size_t)sOz;
    float cs[FB];
#pragma unroll
    for (int fn = 0; fn < FB; ++fn) cs[fn] = 0.f;
#pragma unroll
    for (int fm = 0; fm < FA; ++fm)
#pragma unroll
      for (int fn = 0; fn < FB; ++fn)
#pragma unroll
        for (int r = 0; r < 4; ++r) {
          float e = __expf(acc[fm][fn][r] * scale - 16.f);   // |v| <~ 25
          cs[fn] += e;
          O[(size_t)(r0 + fm * 16 + r) * ldo + (c0 + fn * 16)] = f2bf(e);
        }
    // reduce this wave's 64 rows per column (xor16 folds hi-groups, xor32
    // pairs) then one atomicAdd per column per wm-half (device scope).
#pragma unroll
    for (int fn = 0; fn < FB; ++fn) {
      cs[fn] += __shfl_xor(cs[fn], 16, 64);
      cs[fn] += __shfl_xor(cs[fn], 32, 64);
    }
    if (hi == 0) {
#pragma unroll
      for (int fn = 0; fn < FB; ++fn)
        atomicAdd(&pl[z * (size_t)sPz + (c0 + fn * 16)], cs[fn]);
    }
  }
}

// ---------------- host ----------------
extern "C" void kernel_launch(void* const* d_in, const int* in_sizes, int n_in,
                              void* d_out, int out_size, void* d_ws, size_t ws_size,
                              hipStream_t stream) {
  const float* x  = (const float*)d_in[0];
  const float* Wq = (const float*)d_in[1];
  const float* bq = (const float*)d_in[2];
  const float* Wk = (const float*)d_in[3];
  const float* bk = (const float*)d_in[4];
  const float* Wv = (const float*)d_in[5];
  const float* bv = (const float*)d_in[6];

  char* ws = (char*)d_ws;
  auto alloc = [&](size_t bytes) {
    char* p = ws; ws += (bytes + 255) & ~(size_t)255; return p;
  };
  unsigned short* xpad = (unsigned short*)alloc((size_t)B_ * TPAD_ * D_ * 2);
  unsigned short* Wt   = (unsigned short*)alloc((size_t)KC_ * KC_ * 2);     // [1536 u][1536 k]
  float*          bcat = (float*)alloc((size_t)KC_ * 4);
  unsigned short* QKV  = (unsigned short*)alloc((size_t)B_ * T_ * KC_ * 2); // [B][T][1536]
  unsigned short* Vt   = (unsigned short*)alloc((size_t)B_ * D_ * T_ * 2);
  float* pl   = (float*)alloc((size_t)B_ * T_ * 4);   // colsum L per (z, col)
  size_t used = (size_t)(ws - (char*)d_ws);
  const size_t sAll = (size_t)B_ * T_ * T_ * 2;   // bf16 P, all batches
  const size_t sOne = (size_t)T_ * T_ * 2;
  const int NB = (used + sAll <= ws_size) ? B_ : 1;  // ws-adaptive batching
  unsigned short* Sb = (unsigned short*)alloc(NB == B_ ? sAll : sOne);

  hipMemsetAsync(pl, 0, (size_t)B_ * T_ * 4, stream);
  prep_x<<<dim3(1025, B_), 256, 0, stream>>>(x, xpad);
  transpose_w3<<<dim3(24, 8, 3), 256, 0, stream>>>(Wq, Wk, Wv, Wt,
                                                   bq, bk, bv, bcat);

  // QKV GEMM: M=2048/batch, N=1536, K=1536; BM=128/BN=192 -> 1024 blocks
  // = exactly 2.0 rounds of 512 block-slots (2 blocks/CU, LDS 80KB).
  gemm8<0, 192><<<dim3(16, 8, B_), 256, 0, stream>>>(
      xpad, (long long)TPAD_ * D_, D_,
      Wt, 0, KC_,
      QKV, (long long)T_ * KC_, KC_,
      bcat, nullptr, 0, KC_, 1.0f);

  const float scale = 0.044194173824159216f;  // 1/sqrt(512)
  for (int b0 = 0; b0 < B_; b0 += NB) {
    const unsigned short* Qp = QKV + (size_t)b0 * T_ * KC_;          // +0
    const unsigned short* Kp = QKV + (size_t)b0 * T_ * KC_ + D_;     // +512
    // P_raw = exp(S-16); column sums accumulated atomically into pl[z][col]
    gemm8<1, 128><<<dim3(16, 16, NB), 256, 0, stream>>>(
        Qp, (long long)T_ * KC_, KC_,
        Kp, (long long)T_ * KC_, KC_,
        Sb, (long long)T_ * T_, T_,
        nullptr, pl + (size_t)b0 * T_, (long long)T_,
        D_, scale);
    // Vt[d][k] = V[k][d] / L[k]  (transpose + scale fused, after scores)
    transpose_scale_v<<<dim3(32, 8, NB), 256, 0, stream>>>(
        QKV + (size_t)b0 * T_ * KC_ + 2 * D_,
        Vt + (size_t)b0 * D_ * T_, (long long)D_ * T_,
        pl + (size_t)b0 * T_, (long long)T_);
    // ctx: out = P_raw @ Vt'^T, 128x128 tiles -> 512 blocks
    gemm8<2, 128><<<dim3(16, 4, NB), 256, 0, stream>>>(
        Sb, (long long)T_ * T_, T_,
        Vt + (size_t)b0 * D_ * T_, (long long)D_ * T_, T_,
        (float*)d_out + (size_t)b0 * T_ * D_, (long long)T_ * D_, D_,
        nullptr, nullptr, 0, T_, 1.0f);
  }
}